// Round 2
// baseline (12374.979 us; speedup 1.0000x reference)
//
#include <hip/hip_runtime.h>
#include <hip/hip_bf16.h>
#include <cmath>

// Problem constants
#define B_    4
#define T_    2048
#define DIM_  1024
#define H_    16
#define NOPE_ 128
#define ROPE_ 64
#define VDIM_ 128
#define KVR_  512
#define QKD_  192          // NOPE + ROPE
#define NTOK  (B_ * T_)    // 8192

static constexpr float SCALE_ = 0.07216878364870322f;  // 1/sqrt(192)

typedef __attribute__((ext_vector_type(8))) unsigned short ushort8_t;

// --- load 8 consecutive elements as float ---------------------------------
__device__ inline void load8f(const float* p, float* d) {
    const float4 a = *(const float4*)p;
    const float4 b = *(const float4*)(p + 4);
    d[0]=a.x; d[1]=a.y; d[2]=a.z; d[3]=a.w;
    d[4]=b.x; d[5]=b.y; d[6]=b.z; d[7]=b.w;
}
__device__ inline void load8f(const __hip_bfloat16* p, float* d) {
    ushort8_t u = *(const ushort8_t*)p;
    #pragma unroll
    for (int i = 0; i < 8; ++i)
        d[i] = __uint_as_float(((unsigned int)u[i]) << 16);
}
__device__ inline void store1(float* p, float v)          { *p = v; }
__device__ inline void store1(__hip_bfloat16* p, float v) { *p = __float2bfloat16(v); }

// ---------------------------------------------------------------------------
// Tiled GEMM:  C[m][n] = sum_k A[m][k] * W[n][k] + bias[n]   (fp32 accumulate)
// A: (M, lda) row-major AT, W: (N, K) row-major fp32, C: (M, ldc) CT.
// Tiles: BM=BN=64, BK=32. 256 threads, each computes 4x4.
// Requires M%64==0, N%64==0, K%32==0 (true for all calls).
// ---------------------------------------------------------------------------
template <typename AT, typename CT>
__global__ __launch_bounds__(256) void gemm_nt64(
    const AT* __restrict__ A, int lda,
    const float* __restrict__ W,
    const float* __restrict__ bias,
    CT* __restrict__ C, int ldc, int K)
{
    __shared__ float a_s[32][65];   // [k][m], padded
    __shared__ float w_s[32][65];   // [k][n], padded

    const int tid = threadIdx.x;
    const int n0 = blockIdx.x * 64;
    const int m0 = blockIdx.y * 64;
    const int tx = tid & 15;        // n micro index
    const int ty = tid >> 4;        // m micro index

    const int r  = tid >> 2;        // 0..63 row within tile for loads
    const int c0 = (tid & 3) * 8;   // 0,8,16,24 k-offset for loads

    float acc[4][4] = {};

    const AT*    Arow = A + (size_t)(m0 + r) * lda;
    const float* Wrow = W + (size_t)(n0 + r) * K;

    for (int k0 = 0; k0 < K; k0 += 32) {
        float av8[8], wv8[8];
        load8f(Arow + k0 + c0, av8);
        load8f(Wrow + k0 + c0, wv8);

        #pragma unroll
        for (int i = 0; i < 8; ++i) { a_s[c0+i][r] = av8[i]; w_s[c0+i][r] = wv8[i]; }

        __syncthreads();

        #pragma unroll
        for (int k = 0; k < 32; ++k) {
            float av[4], wv[4];
            #pragma unroll
            for (int i = 0; i < 4; ++i) av[i] = a_s[k][ty*4 + i];
            #pragma unroll
            for (int j = 0; j < 4; ++j) wv[j] = w_s[k][tx*4 + j];
            #pragma unroll
            for (int i = 0; i < 4; ++i)
                #pragma unroll
                for (int j = 0; j < 4; ++j)
                    acc[i][j] += av[i] * wv[j];
        }
        __syncthreads();
    }

    #pragma unroll
    for (int i = 0; i < 4; ++i) {
        CT* crow = C + (size_t)(m0 + ty*4 + i) * ldc + n0 + tx*4;
        #pragma unroll
        for (int j = 0; j < 4; ++j)
            store1(crow + j, acc[i][j] + bias[n0 + tx*4 + j]);
    }
}

// ---------------------------------------------------------------------------
// RoPE on q's last 64 dims of each head. q: (NTOK, H*QKD) bf16.
// Block 512: one thread per (head, freq-pair). Grid: NTOK.
// ---------------------------------------------------------------------------
__global__ __launch_bounds__(512) void rope_q(
    __hip_bfloat16* __restrict__ q,
    const float* __restrict__ cs,   // (T, 32)
    const float* __restrict__ sn)   // (T, 32)
{
    const int tok = blockIdx.x;
    const int tid = threadIdx.x;      // 0..511
    const int h = tid >> 5;           // 0..15
    const int i = tid & 31;           // freq pair
    const int t = tok & (T_ - 1);

    const float c = cs[t*32 + i];
    const float s = sn[t*32 + i];
    __hip_bfloat16* p = q + (size_t)tok * (H_*QKD_) + h*QKD_ + NOPE_ + 2*i;
    const float xr = __bfloat162float(p[0]);
    const float xi = __bfloat162float(p[1]);
    p[0] = __float2bfloat16(xr * c - xi * s);
    p[1] = __float2bfloat16(xr * s + xi * c);
}

// ---------------------------------------------------------------------------
// Fused: RMS-norm kv_a[:, 0:512] in place, RoPE kv_a[:, 512:576] in place.
// kva fp32. Grid: NTOK, block 256.
// ---------------------------------------------------------------------------
__global__ __launch_bounds__(256) void rmsnorm_ropek(
    float* __restrict__ kva,
    const float* __restrict__ cs,
    const float* __restrict__ sn)
{
    const int tok = blockIdx.x;
    const int tid = threadIdx.x;
    float* row = kva + (size_t)tok * (KVR_ + ROPE_);

    const float x0 = row[tid];
    const float x1 = row[tid + 256];
    float ss = x0*x0 + x1*x1;
    #pragma unroll
    for (int off = 32; off >= 1; off >>= 1)
        ss += __shfl_down(ss, off);

    __shared__ float red[4];
    __shared__ float scale_sh;
    if ((tid & 63) == 0) red[tid >> 6] = ss;
    __syncthreads();
    if (tid == 0) {
        const float tot = red[0] + red[1] + red[2] + red[3];
        scale_sh = rsqrtf(tot * (1.0f/512.0f) + 1e-6f);
    }
    __syncthreads();
    const float sc = scale_sh;
    row[tid]       = x0 * sc;
    row[tid + 256] = x1 * sc;

    if (tid < 32) {
        const int t = tok & (T_ - 1);
        const float c = cs[t*32 + tid];
        const float s = sn[t*32 + tid];
        const float xr = row[KVR_ + 2*tid];
        const float xi = row[KVR_ + 2*tid + 1];
        row[KVR_ + 2*tid]     = xr * c - xi * s;
        row[KVR_ + 2*tid + 1] = xr * s + xi * c;
    }
}

// ---------------------------------------------------------------------------
// Flash-style causal attention. One block per (q-tile of 16 rows, head, batch).
// BQ=16, BK=32, online softmax. fp32 compute in LDS/regs, bf16 global I/O.
//   q   : (NTOK, 3072) bf16, head h at h*192, already RoPE'd; pre-scaled here.
//   kv  : (NTOK, 4096) bf16, head h: k_nope at h*256, v at h*256+128.
//   kva : (NTOK, 576) fp32,  rope'd k at cols 512..575 (shared across heads).
//   o   : (NTOK, 2048) bf16, head h at h*128.
// ---------------------------------------------------------------------------
__global__ __launch_bounds__(256) void attn_kernel(
    const __hip_bfloat16* __restrict__ q,
    const __hip_bfloat16* __restrict__ kv,
    const float* __restrict__ kva,
    __hip_bfloat16* __restrict__ o)
{
    __shared__ float q_s[16][193];   // padded: stride 193 kills 192-stride conflicts
    __shared__ float k_s[32][193];
    __shared__ float v_s[32][128];
    __shared__ float s_s[16][32];
    __shared__ float m_s[16], l_s[16], al_s[16];

    const int tid = threadIdx.x;
    const int qt = blockIdx.x, h = blockIdx.y, b = blockIdx.z;
    const int q0 = qt * 16;
    const size_t tokb = (size_t)b * T_;

    for (int e = tid; e < 16*192; e += 256) {
        const int rr = e / 192, cc = e % 192;
        q_s[rr][cc] = __bfloat162float(q[(tokb + q0 + rr) * 3072 + h*QKD_ + cc]) * SCALE_;
    }
    if (tid < 16) { m_s[tid] = -INFINITY; l_s[tid] = 0.0f; }

    float o_r[8] = {};
    const int ro = tid >> 4;   // q row 0..15
    const int cg = tid & 15;   // column group

    const int nkt = (q0 + 16 + 31) / 32;

    for (int kt = 0; kt < nkt; ++kt) {
        const int j0 = kt * 32;

        for (int e = tid; e < 32*192; e += 256) {
            const int jr = e / 192, cc = e % 192;
            const size_t gt = tokb + j0 + jr;
            k_s[jr][cc] = (cc < 128) ? __bfloat162float(kv[gt*4096 + h*256 + cc])
                                     : kva[gt*576 + KVR_ + (cc - 128)];
        }
        for (int e = tid; e < 32*128; e += 256) {
            const int jr = e >> 7, cc = e & 127;
            v_s[jr][cc] = __bfloat162float(kv[(tokb + j0 + jr)*4096 + h*256 + 128 + cc]);
        }
        __syncthreads();

        // S = Qs . K^T  (16x32), causal mask
        #pragma unroll
        for (int rep = 0; rep < 2; ++rep) {
            const int idx = tid + rep*256;
            const int rr = idx >> 5, j = idx & 31;
            const int kpos = j0 + j, qpos = q0 + rr;
            float acc;
            if (kpos <= qpos) {
                acc = 0.0f;
                #pragma unroll 8
                for (int cc = 0; cc < 192; ++cc)
                    acc += q_s[rr][cc] * k_s[j][cc];
            } else {
                acc = -INFINITY;
            }
            s_s[rr][j] = acc;
        }
        __syncthreads();

        // online softmax per row (threads 0..15)
        if (tid < 16) {
            const int rr = tid;
            const float mo = m_s[rr];
            float mx = mo;
            #pragma unroll 8
            for (int j = 0; j < 32; ++j) mx = fmaxf(mx, s_s[rr][j]);
            const float al = __expf(mo - mx);       // first tile: exp(-inf)=0
            float sum = 0.0f;
            #pragma unroll 8
            for (int j = 0; j < 32; ++j) {
                const float p = __expf(s_s[rr][j] - mx);  // masked -> 0
                s_s[rr][j] = p;
                sum += p;
            }
            l_s[rr] = l_s[rr] * al + sum;
            m_s[rr] = mx;
            al_s[rr] = al;
        }
        __syncthreads();

        // O += P . V   (thread owns row ro, cols cg + 16*i)
        const float al = al_s[ro];
        #pragma unroll
        for (int i = 0; i < 8; ++i) o_r[i] *= al;
        #pragma unroll 4
        for (int j = 0; j < 32; ++j) {
            const float p = s_s[ro][j];
            #pragma unroll
            for (int i = 0; i < 8; ++i)
                o_r[i] += p * v_s[j][cg + 16*i];
        }
        __syncthreads();
    }

    const float inv = 1.0f / l_s[ro];
    __hip_bfloat16* orow = o + (tokb + q0 + ro) * 2048 + h*VDIM_;
    #pragma unroll
    for (int i = 0; i < 8; ++i)
        orow[cg + 16*i] = __float2bfloat16(o_r[i] * inv);
}

// Diagnostic fallback: zero the output (fails absmax with a clean signature
// instead of faulting) if the workspace is too small for our layout.
__global__ void fill_zero(float* p, int n) {
    int i = blockIdx.x * 256 + threadIdx.x;
    if (i < n) p[i] = 0.0f;
}

// ---------------------------------------------------------------------------
extern "C" void kernel_launch(void* const* d_in, const int* in_sizes, int n_in,
                              void* d_out, int out_size, void* d_ws, size_t ws_size,
                              hipStream_t stream)
{
    const float* x      = (const float*)d_in[0];
    const float* wq_w   = (const float*)d_in[1];
    const float* wq_b   = (const float*)d_in[2];
    const float* wkva_w = (const float*)d_in[3];
    const float* wkva_b = (const float*)d_in[4];
    const float* wkvb_w = (const float*)d_in[5];
    const float* wkvb_b = (const float*)d_in[6];
    const float* wo_w   = (const float*)d_in[7];
    const float* wo_b   = (const float*)d_in[8];
    const float* cs     = (const float*)d_in[9];
    const float* sn     = (const float*)d_in[10];
    // d_in[11] = start_pos (unused, always 0)

    // Workspace layout (bytes):
    //   q   bf16  8192*3072*2 = 50,331,648
    //   kv  bf16  8192*4096*2 = 67,108,864
    //   att bf16  8192*2048*2 = 33,554,432
    //   kva fp32  8192* 576*4 = 18,874,368
    // total 169,869,312
    const size_t q_bytes   = (size_t)NTOK * 3072 * 2;
    const size_t kv_bytes  = (size_t)NTOK * 4096 * 2;
    const size_t att_bytes = (size_t)NTOK * 2048 * 2;
    const size_t kva_bytes = (size_t)NTOK * 576 * 4;
    const size_t need = q_bytes + kv_bytes + att_bytes + kva_bytes;

    if (ws_size < need) {
        // Workspace too small for this layout: fail cleanly (absmax = ref max),
        // do not corrupt memory.
        fill_zero<<<(out_size + 255) / 256, 256, 0, stream>>>((float*)d_out, out_size);
        return;
    }

    char* wsb = (char*)d_ws;
    __hip_bfloat16* q   = (__hip_bfloat16*)wsb;
    __hip_bfloat16* kv  = (__hip_bfloat16*)(wsb + q_bytes);
    __hip_bfloat16* att = (__hip_bfloat16*)(wsb + q_bytes + kv_bytes);
    float*          kva = (float*)(wsb + q_bytes + kv_bytes + att_bytes);
    float*          out = (float*)d_out;

    // q = x @ wq^T + b          (8192 x 3072, K=1024)
    gemm_nt64<float, __hip_bfloat16><<<dim3(3072/64, NTOK/64), 256, 0, stream>>>(
        x, DIM_, wq_w, wq_b, q, 3072, DIM_);
    // kv_a = x @ wkv_a^T + b    (8192 x 576, K=1024)
    gemm_nt64<float, float><<<dim3(576/64, NTOK/64), 256, 0, stream>>>(
        x, DIM_, wkva_w, wkva_b, kva, 576, DIM_);
    // RoPE on q rope dims
    rope_q<<<NTOK, 512, 0, stream>>>(q, cs, sn);
    // RMS-norm kv_lat in place + RoPE k_rope in place
    rmsnorm_ropek<<<NTOK, 256, 0, stream>>>(kva, cs, sn);
    // kv = rmsnorm(kv_lat) @ wkv_b^T + b   (8192 x 4096, K=512, lda=576)
    gemm_nt64<float, __hip_bfloat16><<<dim3(4096/64, NTOK/64), 256, 0, stream>>>(
        kva, 576, wkvb_w, wkvb_b, kv, 4096, KVR_);
    // causal attention
    attn_kernel<<<dim3(T_/16, H_, B_), 256, 0, stream>>>(q, kv, kva, att);
    // out = att @ wo^T + b      (8192 x 1024, K=2048)
    gemm_nt64<__hip_bfloat16, float><<<dim3(1024/64, NTOK/64), 256, 0, stream>>>(
        att, 2048, wo_w, wo_b, out, DIM_, 2048);
}

// Round 3
// 4133.051 us; speedup vs baseline: 2.9942x; 2.9942x over previous
//
#include <hip/hip_runtime.h>
#include <hip/hip_bf16.h>
#include <cmath>

// Problem constants
#define B_    4
#define T_    2048
#define DIM_  1024
#define H_    16
#define NOPE_ 128
#define ROPE_ 64
#define VDIM_ 128
#define KVR_  512
#define QKD_  192          // NOPE + ROPE
#define NTOK  (B_ * T_)    // 8192

static constexpr float SCALE_ = 0.07216878364870322f;  // 1/sqrt(192)

typedef __attribute__((ext_vector_type(8))) unsigned short ushort8_t;
typedef __bf16 v8bf __attribute__((ext_vector_type(8)));
typedef float  v4f  __attribute__((ext_vector_type(4)));

__device__ inline float bf2f(unsigned short u) {
    return __uint_as_float(((unsigned int)u) << 16);
}
// round-to-nearest-even f32 -> bf16 bits (no NaN handling; inputs are finite)
__device__ inline unsigned short f2bf(float f) {
    unsigned int u = __float_as_uint(f);
    u += 0x7FFFu + ((u >> 16) & 1u);
    return (unsigned short)(u >> 16);
}

// --- load 8 consecutive elements as float ---------------------------------
__device__ inline void load8f(const float* p, float* d) {
    const float4 a = *(const float4*)p;
    const float4 b = *(const float4*)(p + 4);
    d[0]=a.x; d[1]=a.y; d[2]=a.z; d[3]=a.w;
    d[4]=b.x; d[5]=b.y; d[6]=b.z; d[7]=b.w;
}
__device__ inline void load8f(const __hip_bfloat16* p, float* d) {
    ushort8_t u = *(const ushort8_t*)p;
    #pragma unroll
    for (int i = 0; i < 8; ++i) d[i] = bf2f(u[i]);
}
__device__ inline void store1(float* p, float v)          { *p = v; }
__device__ inline void store1(__hip_bfloat16* p, float v) { *p = __float2bfloat16(v); }

// ---------------------------------------------------------------------------
// Tiled GEMM:  C[m][n] = sum_k A[m][k] * W[n][k] + bias[n]   (fp32 accumulate)
// ---------------------------------------------------------------------------
template <typename AT, typename CT>
__global__ __launch_bounds__(256) void gemm_nt64(
    const AT* __restrict__ A, int lda,
    const float* __restrict__ W,
    const float* __restrict__ bias,
    CT* __restrict__ C, int ldc, int K)
{
    __shared__ float a_s[32][65];   // [k][m], padded
    __shared__ float w_s[32][65];   // [k][n], padded

    const int tid = threadIdx.x;
    const int n0 = blockIdx.x * 64;
    const int m0 = blockIdx.y * 64;
    const int tx = tid & 15;        // n micro index
    const int ty = tid >> 4;        // m micro index

    const int r  = tid >> 2;        // 0..63 row within tile for loads
    const int c0 = (tid & 3) * 8;   // 0,8,16,24 k-offset for loads

    float acc[4][4] = {};

    const AT*    Arow = A + (size_t)(m0 + r) * lda;
    const float* Wrow = W + (size_t)(n0 + r) * K;

    for (int k0 = 0; k0 < K; k0 += 32) {
        float av8[8], wv8[8];
        load8f(Arow + k0 + c0, av8);
        load8f(Wrow + k0 + c0, wv8);

        #pragma unroll
        for (int i = 0; i < 8; ++i) { a_s[c0+i][r] = av8[i]; w_s[c0+i][r] = wv8[i]; }

        __syncthreads();

        #pragma unroll
        for (int k = 0; k < 32; ++k) {
            float av[4], wv[4];
            #pragma unroll
            for (int i = 0; i < 4; ++i) av[i] = a_s[k][ty*4 + i];
            #pragma unroll
            for (int j = 0; j < 4; ++j) wv[j] = w_s[k][tx*4 + j];
            #pragma unroll
            for (int i = 0; i < 4; ++i)
                #pragma unroll
                for (int j = 0; j < 4; ++j)
                    acc[i][j] += av[i] * wv[j];
        }
        __syncthreads();
    }

    #pragma unroll
    for (int i = 0; i < 4; ++i) {
        CT* crow = C + (size_t)(m0 + ty*4 + i) * ldc + n0 + tx*4;
        #pragma unroll
        for (int j = 0; j < 4; ++j)
            store1(crow + j, acc[i][j] + bias[n0 + tx*4 + j]);
    }
}

// ---------------------------------------------------------------------------
// RoPE on q's last 64 dims of each head. q: (NTOK, H*QKD) bf16.
// ---------------------------------------------------------------------------
__global__ __launch_bounds__(512) void rope_q(
    __hip_bfloat16* __restrict__ q,
    const float* __restrict__ cs,   // (T, 32)
    const float* __restrict__ sn)   // (T, 32)
{
    const int tok = blockIdx.x;
    const int tid = threadIdx.x;      // 0..511
    const int h = tid >> 5;           // 0..15
    const int i = tid & 31;           // freq pair
    const int t = tok & (T_ - 1);

    const float c = cs[t*32 + i];
    const float s = sn[t*32 + i];
    __hip_bfloat16* p = q + (size_t)tok * (H_*QKD_) + h*QKD_ + NOPE_ + 2*i;
    const float xr = __bfloat162float(p[0]);
    const float xi = __bfloat162float(p[1]);
    p[0] = __float2bfloat16(xr * c - xi * s);
    p[1] = __float2bfloat16(xr * s + xi * c);
}

// ---------------------------------------------------------------------------
// Fused: RMS-norm kv_a[:, 0:512] in place, RoPE kv_a[:, 512:576] in place.
// ---------------------------------------------------------------------------
__global__ __launch_bounds__(256) void rmsnorm_ropek(
    float* __restrict__ kva,
    const float* __restrict__ cs,
    const float* __restrict__ sn)
{
    const int tok = blockIdx.x;
    const int tid = threadIdx.x;
    float* row = kva + (size_t)tok * (KVR_ + ROPE_);

    const float x0 = row[tid];
    const float x1 = row[tid + 256];
    float ss = x0*x0 + x1*x1;
    #pragma unroll
    for (int off = 32; off >= 1; off >>= 1)
        ss += __shfl_down(ss, off);

    __shared__ float red[4];
    __shared__ float scale_sh;
    if ((tid & 63) == 0) red[tid >> 6] = ss;
    __syncthreads();
    if (tid == 0) {
        const float tot = red[0] + red[1] + red[2] + red[3];
        scale_sh = rsqrtf(tot * (1.0f/512.0f) + 1e-6f);
    }
    __syncthreads();
    const float sc = scale_sh;
    row[tid]       = x0 * sc;
    row[tid + 256] = x1 * sc;

    if (tid < 32) {
        const int t = tok & (T_ - 1);
        const float c = cs[t*32 + tid];
        const float s = sn[t*32 + tid];
        const float xr = row[KVR_ + 2*tid];
        const float xi = row[KVR_ + 2*tid + 1];
        row[KVR_ + 2*tid]     = xr * c - xi * s;
        row[KVR_ + 2*tid + 1] = xr * s + xi * c;
    }
}

// ---------------------------------------------------------------------------
// MFMA flash attention. BQ=64, BK=64, 4 waves; wave w owns q rows w*16..+15.
//   q   : (NTOK, 3072) bf16, head h at h*192, RoPE'd. Pre-scaled on load.
//   kv  : (NTOK, 4096) bf16, head h: k_nope at h*256, v at h*256+128.
//   kva : (NTOK, 576) fp32,  rope'd k at cols 512..575 (shared across heads).
//   att : (NTOK, 2048) bf16, head h at h*128.
// MFMA layouts (m89/m91-verified): A[m=lane&15][k=quad*8+j];
// B[k=quad*8+j][n=lane&15]; C col=lane&15, row=quad*4+reg.
// ---------------------------------------------------------------------------
__global__ __launch_bounds__(256) void attn_mfma(
    const __hip_bfloat16* __restrict__ q,
    const __hip_bfloat16* __restrict__ kv,
    const float* __restrict__ kva,
    __hip_bfloat16* __restrict__ att)
{
    __shared__ unsigned short K_s[64][200];   // [ktok][d], pad 192->200 (2-way banks)
    __shared__ unsigned short Vt_s[128][72];  // [v][ktok] transposed, pad 64->72
    __shared__ unsigned short P_s[64][72];    // [qrow][ktok], pad 64->72

    const int tid  = threadIdx.x;
    const int ln   = tid & 15;
    const int quad = (tid & 63) >> 4;
    const int wv   = tid >> 6;

    const int qt = (int)(gridDim.x - 1) - (int)blockIdx.x;  // big tiles dispatch first
    const int h  = blockIdx.y, b = blockIdx.z;
    const int q0 = qt * 64;
    const size_t tokb = (size_t)b * T_;

    // ---- Q fragments into registers (A layout), pre-scaled ----
    v8bf qf[6];
    {
        const __hip_bfloat16* qrow =
            q + (tokb + q0 + wv*16 + ln) * (size_t)(H_*QKD_) + h*QKD_;
        #pragma unroll
        for (int s = 0; s < 6; ++s) {
            ushort8_t raw = *(const ushort8_t*)(qrow + s*32 + quad*8);
            ushort8_t sc;
            #pragma unroll
            for (int i = 0; i < 8; ++i)
                sc[i] = f2bf(bf2f(raw[i]) * SCALE_);
            qf[s] = __builtin_bit_cast(v8bf, sc);
        }
    }

    v4f O[8];
    #pragma unroll
    for (int nt = 0; nt < 8; ++nt) O[nt] = (v4f){0.f, 0.f, 0.f, 0.f};
    float m_r[4], l_r[4];
    #pragma unroll
    for (int r = 0; r < 4; ++r) { m_r[r] = -1e30f; l_r[r] = 0.0f; }

    const int nkt = qt + 1;
    for (int kt = 0; kt < nkt; ++kt) {
        const int j0 = kt * 64;
        __syncthreads();   // prior iteration's LDS reads complete before overwrite

        // ---- stage K (nope from kv bf16, rope from kva fp32->bf16) ----
        #pragma unroll
        for (int it = 0; it < 4; ++it) {
            const int idx = tid + it*256;
            const int j = idx >> 4, g = idx & 15;
            *(ushort8_t*)&K_s[j][g*8] =
                *(const ushort8_t*)(kv + (tokb + j0 + j)*4096 + h*256 + g*8);
        }
        #pragma unroll
        for (int it = 0; it < 2; ++it) {
            const int idx = tid + it*256;
            const int j = idx >> 3, g = idx & 7;
            const float* src = kva + (tokb + j0 + j)*576 + KVR_ + g*8;
            const float4 f0 = *(const float4*)src;
            const float4 f1 = *(const float4*)(src + 4);
            ushort8_t u;
            u[0]=f2bf(f0.x); u[1]=f2bf(f0.y); u[2]=f2bf(f0.z); u[3]=f2bf(f0.w);
            u[4]=f2bf(f1.x); u[5]=f2bf(f1.y); u[6]=f2bf(f1.z); u[7]=f2bf(f1.w);
            *(ushort8_t*)&K_s[j][128 + g*8] = u;
        }
        // ---- stage V transposed (coalesced global read, swizzled LDS write) ----
        #pragma unroll
        for (int it = 0; it < 4; ++it) {
            const int idx = tid + it*256;
            const int j = idx >> 4, g = idx & 15;
            ushort8_t v = *(const ushort8_t*)(kv + (tokb + j0 + j)*4096 + h*256 + 128 + g*8);
            #pragma unroll
            for (int i = 0; i < 8; ++i) {
                const int ii = (i + g) & 7;   // swizzle: spreads banks across lanes
                Vt_s[g*8 + ii][j] = v[ii];
            }
        }
        __syncthreads();

        // ---- S = Q K^T  (wave: 16 q-rows x 64 k-tokens) ----
        v4f S[4];
        #pragma unroll
        for (int t = 0; t < 4; ++t) S[t] = (v4f){0.f, 0.f, 0.f, 0.f};
        #pragma unroll
        for (int s = 0; s < 6; ++s) {
            #pragma unroll
            for (int t = 0; t < 4; ++t) {
                const v8bf kb = *(const v8bf*)&K_s[t*16 + ln][s*32 + quad*8];
                S[t] = __builtin_amdgcn_mfma_f32_16x16x32_bf16(qf[s], kb, S[t], 0, 0, 0);
            }
        }

        // ---- causal mask: only the diagonal k-tile needs it ----
        if (kt == nkt - 1) {
            #pragma unroll
            for (int t = 0; t < 4; ++t) {
                const int kpos = j0 + t*16 + ln;
                #pragma unroll
                for (int r = 0; r < 4; ++r) {
                    const int qpos = q0 + wv*16 + quad*4 + r;
                    if (kpos > qpos) S[t][r] = -1e30f;
                }
            }
        }

        // ---- online softmax (rows live in regs, reduce across 16 lanes) ----
        float alpha[4];
        #pragma unroll
        for (int r = 0; r < 4; ++r) {
            float mx = fmaxf(fmaxf(S[0][r], S[1][r]), fmaxf(S[2][r], S[3][r]));
            #pragma unroll
            for (int off = 1; off < 16; off <<= 1)
                mx = fmaxf(mx, __shfl_xor(mx, off));
            const float mn = fmaxf(m_r[r], mx);
            alpha[r] = __expf(m_r[r] - mn);
            m_r[r] = mn;
        }
        float rs[4] = {0.f, 0.f, 0.f, 0.f};
        #pragma unroll
        for (int t = 0; t < 4; ++t)
            #pragma unroll
            for (int r = 0; r < 4; ++r) {
                const float p = __expf(S[t][r] - m_r[r]);
                S[t][r] = p;
                rs[r] += p;
            }
        #pragma unroll
        for (int r = 0; r < 4; ++r) {
            #pragma unroll
            for (int off = 1; off < 16; off <<= 1)
                rs[r] += __shfl_xor(rs[r], off);
            l_r[r] = l_r[r]*alpha[r] + rs[r];
        }

        // ---- P: C layout -> LDS -> A layout (per-wave-private rows) ----
        #pragma unroll
        for (int t = 0; t < 4; ++t)
            #pragma unroll
            for (int r = 0; r < 4; ++r)
                P_s[wv*16 + quad*4 + r][t*16 + ln] = f2bf(S[t][r]);

        // ---- rescale O, then O += P V ----
        #pragma unroll
        for (int nt = 0; nt < 8; ++nt)
            #pragma unroll
            for (int r = 0; r < 4; ++r)
                O[nt][r] *= alpha[r];

        #pragma unroll
        for (int s = 0; s < 2; ++s) {
            const v8bf pa = *(const v8bf*)&P_s[wv*16 + ln][s*32 + quad*8];
            #pragma unroll
            for (int nt = 0; nt < 8; ++nt) {
                const v8bf vb = *(const v8bf*)&Vt_s[nt*16 + ln][s*32 + quad*8];
                O[nt] = __builtin_amdgcn_mfma_f32_16x16x32_bf16(pa, vb, O[nt], 0, 0, 0);
            }
        }
    }

    // ---- epilogue: O / l -> att (C layout rows) ----
    __hip_bfloat16* obase = att + (tokb + q0 + wv*16) * (size_t)(H_*VDIM_) + h*VDIM_;
    #pragma unroll
    for (int r = 0; r < 4; ++r) {
        const float inv = 1.0f / l_r[r];
        __hip_bfloat16* orow = obase + (size_t)(quad*4 + r) * (H_*VDIM_);
        #pragma unroll
        for (int nt = 0; nt < 8; ++nt)
            orow[nt*16 + ln] = __float2bfloat16(O[nt][r] * inv);
    }
}

// Diagnostic fallback: zero the output if workspace is too small.
__global__ void fill_zero(float* p, int n) {
    int i = blockIdx.x * 256 + threadIdx.x;
    if (i < n) p[i] = 0.0f;
}

// ---------------------------------------------------------------------------
extern "C" void kernel_launch(void* const* d_in, const int* in_sizes, int n_in,
                              void* d_out, int out_size, void* d_ws, size_t ws_size,
                              hipStream_t stream)
{
    const float* x      = (const float*)d_in[0];
    const float* wq_w   = (const float*)d_in[1];
    const float* wq_b   = (const float*)d_in[2];
    const float* wkva_w = (const float*)d_in[3];
    const float* wkva_b = (const float*)d_in[4];
    const float* wkvb_w = (const float*)d_in[5];
    const float* wkvb_b = (const float*)d_in[6];
    const float* wo_w   = (const float*)d_in[7];
    const float* wo_b   = (const float*)d_in[8];
    const float* cs     = (const float*)d_in[9];
    const float* sn     = (const float*)d_in[10];

    const size_t q_bytes   = (size_t)NTOK * 3072 * 2;
    const size_t kv_bytes  = (size_t)NTOK * 4096 * 2;
    const size_t att_bytes = (size_t)NTOK * 2048 * 2;
    const size_t kva_bytes = (size_t)NTOK * 576 * 4;
    const size_t need = q_bytes + kv_bytes + att_bytes + kva_bytes;

    if (ws_size < need) {
        fill_zero<<<(out_size + 255) / 256, 256, 0, stream>>>((float*)d_out, out_size);
        return;
    }

    char* wsb = (char*)d_ws;
    __hip_bfloat16* q   = (__hip_bfloat16*)wsb;
    __hip_bfloat16* kv  = (__hip_bfloat16*)(wsb + q_bytes);
    __hip_bfloat16* att = (__hip_bfloat16*)(wsb + q_bytes + kv_bytes);
    float*          kva = (float*)(wsb + q_bytes + kv_bytes + att_bytes);
    float*          out = (float*)d_out;

    // q = x @ wq^T + b          (8192 x 3072, K=1024)
    gemm_nt64<float, __hip_bfloat16><<<dim3(3072/64, NTOK/64), 256, 0, stream>>>(
        x, DIM_, wq_w, wq_b, q, 3072, DIM_);
    // kv_a = x @ wkv_a^T + b    (8192 x 576, K=1024)
    gemm_nt64<float, float><<<dim3(576/64, NTOK/64), 256, 0, stream>>>(
        x, DIM_, wkva_w, wkva_b, kva, 576, DIM_);
    // RoPE on q rope dims
    rope_q<<<NTOK, 512, 0, stream>>>(q, cs, sn);
    // RMS-norm kv_lat in place + RoPE k_rope in place
    rmsnorm_ropek<<<NTOK, 256, 0, stream>>>(kva, cs, sn);
    // kv = rmsnorm(kv_lat) @ wkv_b^T + b   (8192 x 4096, K=512, lda=576)
    gemm_nt64<float, __hip_bfloat16><<<dim3(4096/64, NTOK/64), 256, 0, stream>>>(
        kva, 576, wkvb_w, wkvb_b, kv, 4096, KVR_);
    // MFMA flash attention
    attn_mfma<<<dim3(T_/64, H_, B_), 256, 0, stream>>>(q, kv, kva, att);
    // out = att @ wo^T + b      (8192 x 1024, K=2048)
    gemm_nt64<__hip_bfloat16, float><<<dim3(1024/64, NTOK/64), 256, 0, stream>>>(
        att, 2048, wo_w, wo_b, out, DIM_, 2048);
}

// Round 5
// 996.869 us; speedup vs baseline: 12.4138x; 4.1460x over previous
//
#include <hip/hip_runtime.h>
#include <hip/hip_bf16.h>
#include <cmath>

// Problem constants
#define B_    4
#define T_    2048
#define DIM_  1024
#define H_    16
#define NOPE_ 128
#define ROPE_ 64
#define VDIM_ 128
#define KVR_  512
#define QKD_  192          // NOPE + ROPE
#define NTOK  (B_ * T_)    // 8192

static constexpr float SCALE_ = 0.07216878364870322f;  // 1/sqrt(192)

typedef __attribute__((ext_vector_type(8))) unsigned short ushort8_t;
typedef __bf16 v8bf __attribute__((ext_vector_type(8)));
typedef float  v4f  __attribute__((ext_vector_type(4)));

__device__ __forceinline__ float bf2f(unsigned short u) {
    return __uint_as_float(((unsigned int)u) << 16);
}
// round-to-nearest-even f32 -> bf16 bits (finite inputs)
__device__ __forceinline__ unsigned short f2bf(float f) {
    unsigned int u = __float_as_uint(f);
    u += 0x7FFFu + ((u >> 16) & 1u);
    return (unsigned short)(u >> 16);
}
__device__ __forceinline__ void store1(float* p, float v)          { *p = v; }
__device__ __forceinline__ void store1(__hip_bfloat16* p, float v) { *p = __float2bfloat16(v); }

// async global->LDS, 16B per lane. LDS dest = wave-uniform base + lane*16.
__device__ __forceinline__ void load_lds16(const void* g, void* l) {
    __builtin_amdgcn_global_load_lds(
        (const __attribute__((address_space(1))) void*)g,
        (__attribute__((address_space(3))) void*)l, 16, 0, 0);
}

// ---------------------------------------------------------------------------
// fp32 -> bf16 conversion (n % 4 == 0)
// ---------------------------------------------------------------------------
__global__ __launch_bounds__(256) void cvt_bf16(
    const float* __restrict__ s, __hip_bfloat16* __restrict__ d, int n)
{
    const int i = (blockIdx.x * 256 + threadIdx.x) * 4;
    if (i < n) {
        const float4 v = *(const float4*)(s + i);
        ushort4 o;
        o.x = f2bf(v.x); o.y = f2bf(v.y); o.z = f2bf(v.z); o.w = f2bf(v.w);
        *(ushort4*)((unsigned short*)d + i) = o;
    }
}

// wkv_a: (576,1024) fp32 -> (640,1024) bf16 zero-padded; bias 576 -> 640 fp32
__global__ __launch_bounds__(256) void cvt_pad_kva(
    const float* __restrict__ w, const float* __restrict__ b,
    __hip_bfloat16* __restrict__ wd, float* __restrict__ bd)
{
    const int gid = blockIdx.x * 256 + threadIdx.x;
    const int i = gid * 4;                     // over 640*1024
    if (i < 640 * 1024) {
        ushort4 o;
        if (i < 576 * 1024) {
            const float4 v = *(const float4*)(w + i);
            o.x = f2bf(v.x); o.y = f2bf(v.y); o.z = f2bf(v.z); o.w = f2bf(v.w);
        } else {
            o.x = o.y = o.z = o.w = 0;
        }
        *(ushort4*)((unsigned short*)wd + i) = o;
    }
    if (gid < 640) bd[gid] = (gid < 576) ? b[gid] : 0.0f;
}

// ---------------------------------------------------------------------------
// MFMA GEMM: C[m][n] = sum_k A[m][k]*W[n][k] + bias[n]. A,W bf16, acc fp32.
// Tiles 128x128xBK32, 4 waves (2x2 of 64x64), 16x16x32 MFMA.
// EPI=0: plain store to C (CT float/bf16).
// EPI=1: kv_b split epilogue: even 128-tiles -> kn (NTOK,2048) bf16,
//        odd tiles -> vt[h][vd][tok] transposed bf16 (ushort4-packed rows).
// ---------------------------------------------------------------------------
template <typename CT, int EPI>
__global__ __launch_bounds__(256) void gemm_mfma(
    const __hip_bfloat16* __restrict__ A, int lda,
    const __hip_bfloat16* __restrict__ W, int ldw,
    const float* __restrict__ bias,
    CT* __restrict__ C, int ldc, int K,
    __hip_bfloat16* __restrict__ vt)
{
    __shared__ unsigned short A_s[128 * 32];
    __shared__ unsigned short B_s[128 * 32];

    const int tid  = threadIdx.x;
    const int ln   = tid & 63;
    const int wv   = tid >> 6;
    const int l15  = ln & 15;
    const int quad = ln >> 4;
    const int wm   = wv & 1, wn = wv >> 1;
    const int n0 = blockIdx.x * 128, m0 = blockIdx.y * 128;

    v4f acc[4][4] = {};

    for (int k0 = 0; k0 < K; k0 += 32) {
        __syncthreads();
        #pragma unroll
        for (int it = 0; it < 2; ++it) {
            const int idx = it * 256 + wv * 64;   // wave-uniform LDS slot base
            const int li  = idx + ln;             // this lane's slot
            const int row = li >> 2, ch = li & 3; // 128 rows x 4 chunks of 16B
            load_lds16(A + (size_t)(m0 + row) * lda + k0 + ch * 8, &A_s[idx * 8]);
            load_lds16(W + (size_t)(n0 + row) * ldw + k0 + ch * 8, &B_s[idx * 8]);
        }
        __syncthreads();

        v8bf af[4], bf_[4];
        #pragma unroll
        for (int i = 0; i < 4; ++i) {
            af[i]  = *(const v8bf*)&A_s[(wm * 64 + i * 16 + l15) * 32 + quad * 8];
            bf_[i] = *(const v8bf*)&B_s[(wn * 64 + i * 16 + l15) * 32 + quad * 8];
        }
        #pragma unroll
        for (int i = 0; i < 4; ++i)
            #pragma unroll
            for (int j = 0; j < 4; ++j)
                acc[i][j] = __builtin_amdgcn_mfma_f32_16x16x32_bf16(
                                af[i], bf_[j], acc[i][j], 0, 0, 0);
    }

    // epilogue: C row = m0+wm*64+i*16+quad*4+r, col = n0+wn*64+j*16+l15
    if (EPI == 0) {
        #pragma unroll
        for (int i = 0; i < 4; ++i) {
            const int mrow = m0 + wm * 64 + i * 16 + quad * 4;
            #pragma unroll
            for (int j = 0; j < 4; ++j) {
                const int ncol = n0 + wn * 64 + j * 16 + l15;
                const float bb = bias[ncol];
                #pragma unroll
                for (int r = 0; r < 4; ++r)
                    store1(C + (size_t)(mrow + r) * ldc + ncol, acc[i][j][r] + bb);
            }
        }
    } else {
        const int head = n0 >> 8;
        const bool is_v = (n0 & 128) != 0;
        #pragma unroll
        for (int i = 0; i < 4; ++i) {
            const int mrow = m0 + wm * 64 + i * 16 + quad * 4;
            #pragma unroll
            for (int j = 0; j < 4; ++j) {
                const int ncl = wn * 64 + j * 16 + l15;        // 0..127 within tile
                const float bb = bias[n0 + ncl];
                if (!is_v) {
                    __hip_bfloat16* kn = (__hip_bfloat16*)C;
                    #pragma unroll
                    for (int r = 0; r < 4; ++r)
                        kn[(size_t)(mrow + r) * 2048 + head * 128 + ncl] =
                            __float2bfloat16(acc[i][j][r] + bb);
                } else {
                    ushort4 pk;
                    pk.x = f2bf(acc[i][j][0] + bb);
                    pk.y = f2bf(acc[i][j][1] + bb);
                    pk.z = f2bf(acc[i][j][2] + bb);
                    pk.w = f2bf(acc[i][j][3] + bb);
                    *(ushort4*)((unsigned short*)vt +
                                ((size_t)head * 128 + ncl) * NTOK + mrow) = pk;
                }
            }
        }
    }
}

// ---------------------------------------------------------------------------
// RoPE on q's last 64 dims of each head. q: (NTOK, H*QKD) bf16.
// ---------------------------------------------------------------------------
__global__ __launch_bounds__(512) void rope_q(
    __hip_bfloat16* __restrict__ q,
    const float* __restrict__ cs,   // (T, 32)
    const float* __restrict__ sn)
{
    const int tok = blockIdx.x;
    const int tid = threadIdx.x;
    const int h = tid >> 5;
    const int i = tid & 31;
    const int t = tok & (T_ - 1);

    const float c = cs[t*32 + i];
    const float s = sn[t*32 + i];
    __hip_bfloat16* p = q + (size_t)tok * (H_*QKD_) + h*QKD_ + NOPE_ + 2*i;
    const float xr = __bfloat162float(p[0]);
    const float xi = __bfloat162float(p[1]);
    p[0] = __float2bfloat16(xr * c - xi * s);
    p[1] = __float2bfloat16(xr * s + xi * c);
}

// ---------------------------------------------------------------------------
// RMS-norm kv_a[:,0:512] -> kvn bf16 (NTOK,512); RoPE kv_a[:,512:576] -> kr
// bf16 (NTOK,64). Input kva bf16 (NTOK,640). Grid NTOK, block 256.
// ---------------------------------------------------------------------------
__global__ __launch_bounds__(256) void rmsnorm_ropek(
    const __hip_bfloat16* __restrict__ kva,
    __hip_bfloat16* __restrict__ kvn,
    __hip_bfloat16* __restrict__ kr,
    const float* __restrict__ cs,
    const float* __restrict__ sn)
{
    const int tok = blockIdx.x;
    const int tid = threadIdx.x;
    const __hip_bfloat16* row = kva + (size_t)tok * 640;

    const float x0 = __bfloat162float(row[tid]);
    const float x1 = __bfloat162float(row[tid + 256]);
    float ss = x0*x0 + x1*x1;
    #pragma unroll
    for (int off = 32; off >= 1; off >>= 1)
        ss += __shfl_down(ss, off);

    __shared__ float red[4];
    __shared__ float scale_sh;
    if ((tid & 63) == 0) red[tid >> 6] = ss;
    __syncthreads();
    if (tid == 0) {
        const float tot = red[0] + red[1] + red[2] + red[3];
        scale_sh = rsqrtf(tot * (1.0f/512.0f) + 1e-6f);
    }
    __syncthreads();
    const float sc = scale_sh;
    kvn[(size_t)tok*512 + tid]       = __float2bfloat16(x0 * sc);
    kvn[(size_t)tok*512 + tid + 256] = __float2bfloat16(x1 * sc);

    if (tid < 32) {
        const int t = tok & (T_ - 1);
        const float c = cs[t*32 + tid];
        const float s = sn[t*32 + tid];
        const float xr = __bfloat162float(row[KVR_ + 2*tid]);
        const float xi = __bfloat162float(row[KVR_ + 2*tid + 1]);
        kr[(size_t)tok*64 + 2*tid]     = __float2bfloat16(xr * c - xi * s);
        kr[(size_t)tok*64 + 2*tid + 1] = __float2bfloat16(xr * s + xi * c);
    }
}

// ---------------------------------------------------------------------------
// MFMA flash attention. BQ=64, BK=64, 4 waves; wave w owns q rows w*16..+15.
//   q  : (NTOK, 3072) bf16, head h at h*192, RoPE'd. Pre-scaled on load.
//   kn : (NTOK, 2048) bf16, head h k_nope at h*128.
//   kr : (NTOK, 64) bf16, shared rope'd k.
//   vt : (H,128,NTOK) bf16, V pre-transposed.
//   att: (NTOK, 2048) bf16, head h at h*128.
// ---------------------------------------------------------------------------
__global__ __launch_bounds__(256) void attn_mfma(
    const __hip_bfloat16* __restrict__ q,
    const __hip_bfloat16* __restrict__ kn,
    const __hip_bfloat16* __restrict__ kr,
    const __hip_bfloat16* __restrict__ vt,
    __hip_bfloat16* __restrict__ att)
{
    __shared__ unsigned short K_s[64][200];   // [ktok][d], pad 192->200
    __shared__ unsigned short Vt_s[128][72];  // [vd][ktok], pad 64->72
    __shared__ unsigned short P_s[64][72];    // [qrow][ktok], pad 64->72

    const int tid  = threadIdx.x;
    const int ln   = tid & 15;
    const int quad = (tid & 63) >> 4;
    const int wv   = tid >> 6;

    const int qt = (int)(gridDim.x - 1) - (int)blockIdx.x;  // big tiles first
    const int h  = blockIdx.y, b = blockIdx.z;
    const int q0 = qt * 64;
    const size_t tokb = (size_t)b * T_;

    // Q fragments (A layout), pre-scaled
    v8bf qf[6];
    {
        const __hip_bfloat16* qrow =
            q + (tokb + q0 + wv*16 + ln) * (size_t)(H_*QKD_) + h*QKD_;
        #pragma unroll
        for (int s = 0; s < 6; ++s) {
            ushort8_t raw = *(const ushort8_t*)(qrow + s*32 + quad*8);
            ushort8_t sc;
            #pragma unroll
            for (int i = 0; i < 8; ++i)
                sc[i] = f2bf(bf2f(raw[i]) * SCALE_);
            qf[s] = __builtin_bit_cast(v8bf, sc);
        }
    }

    v4f O[8];
    #pragma unroll
    for (int nt = 0; nt < 8; ++nt) O[nt] = (v4f){0.f, 0.f, 0.f, 0.f};
    float m_r[4], l_r[4];
    #pragma unroll
    for (int r = 0; r < 4; ++r) { m_r[r] = -1e30f; l_r[r] = 0.0f; }

    const int nkt = qt + 1;
    for (int kt = 0; kt < nkt; ++kt) {
        const int j0 = kt * 64;
        __syncthreads();

        // stage K nope: 64 rows x 128 cols = 1024 slots of 8 -> 4 iters
        #pragma unroll
        for (int it = 0; it < 4; ++it) {
            const int idx = tid + it*256;
            const int j = idx >> 4, g = idx & 15;
            *(ushort8_t*)&K_s[j][g*8] =
                *(const ushort8_t*)(kn + (tokb + j0 + j)*2048 + h*128 + g*8);
        }
        // stage K rope: 64 rows x 64 cols = 512 slots -> 2 iters
        #pragma unroll
        for (int it = 0; it < 2; ++it) {
            const int idx = tid + it*256;
            const int j = idx >> 3, g = idx & 7;
            *(ushort8_t*)&K_s[j][128 + g*8] =
                *(const ushort8_t*)(kr + (tokb + j0 + j)*64 + g*8);
        }
        // stage V^T: 128 vd x 64 toks = 1024 slots -> 4 iters
        #pragma unroll
        for (int it = 0; it < 4; ++it) {
            const int idx = tid + it*256;
            const int vd = idx >> 3, jc = idx & 7;
            *(ushort8_t*)&Vt_s[vd][jc*8] =
                *(const ushort8_t*)(vt + ((size_t)h*128 + vd)*NTOK + tokb + j0 + jc*8);
        }
        __syncthreads();

        // S = Q K^T (16 q-rows x 64 k-tokens per wave)
        v4f S[4];
        #pragma unroll
        for (int t = 0; t < 4; ++t) S[t] = (v4f){0.f, 0.f, 0.f, 0.f};
        #pragma unroll
        for (int s = 0; s < 6; ++s) {
            #pragma unroll
            for (int t = 0; t < 4; ++t) {
                const v8bf kb = *(const v8bf*)&K_s[t*16 + ln][s*32 + quad*8];
                S[t] = __builtin_amdgcn_mfma_f32_16x16x32_bf16(qf[s], kb, S[t], 0, 0, 0);
            }
        }

        // causal mask on the diagonal tile only
        if (kt == nkt - 1) {
            #pragma unroll
            for (int t = 0; t < 4; ++t) {
                const int kpos = j0 + t*16 + ln;
                #pragma unroll
                for (int r = 0; r < 4; ++r) {
                    const int qpos = q0 + wv*16 + quad*4 + r;
                    if (kpos > qpos) S[t][r] = -1e30f;
                }
            }
        }

        // online softmax (reduce across the 16-lane row groups)
        float alpha[4];
        #pragma unroll
        for (int r = 0; r < 4; ++r) {
            float mx = fmaxf(fmaxf(S[0][r], S[1][r]), fmaxf(S[2][r], S[3][r]));
            #pragma unroll
            for (int off = 1; off < 16; off <<= 1)
                mx = fmaxf(mx, __shfl_xor(mx, off));
            const float mn = fmaxf(m_r[r], mx);
            alpha[r] = __expf(m_r[r] - mn);
            m_r[r] = mn;
        }
        float rs[4] = {0.f, 0.f, 0.f, 0.f};
        #pragma unroll
        for (int t = 0; t < 4; ++t)
            #pragma unroll
            for (int r = 0; r < 4; ++r) {
                const float p = __expf(S[t][r] - m_r[r]);
                S[t][r] = p;
                rs[r] += p;
            }
        #pragma unroll
        for (int r = 0; r < 4; ++r) {
            #pragma unroll
            for (int off = 1; off < 16; off <<= 1)
                rs[r] += __shfl_xor(rs[r], off);
            l_r[r] = l_r[r]*alpha[r] + rs[r];
        }

        // P: C layout -> LDS -> A layout (wave-private rows)
        #pragma unroll
        for (int t = 0; t < 4; ++t)
            #pragma unroll
            for (int r = 0; r < 4; ++r)
                P_s[wv*16 + quad*4 + r][t*16 + ln] = f2bf(S[t][r]);

        #pragma unroll
        for (int nt = 0; nt < 8; ++nt)
            #pragma unroll
            for (int r = 0; r < 4; ++r)
                O[nt][r] *= alpha[r];

        #pragma unroll
        for (int s = 0; s < 2; ++s) {
            const v8bf pa = *(const v8bf*)&P_s[wv*16 + ln][s*32 + quad*8];
            #pragma unroll
            for (int nt = 0; nt < 8; ++nt) {
                const v8bf vb = *(const v8bf*)&Vt_s[nt*16 + ln][s*32 + quad*8];
                O[nt] = __builtin_amdgcn_mfma_f32_16x16x32_bf16(pa, vb, O[nt], 0, 0, 0);
            }
        }
    }

    const float inv0 = 1.0f / l_r[0];
    __hip_bfloat16* obase = att + (tokb + q0 + wv*16) * (size_t)(H_*VDIM_) + h*VDIM_;
    #pragma unroll
    for (int r = 0; r < 4; ++r) {
        const float inv = (r == 0) ? inv0 : 1.0f / l_r[r];
        __hip_bfloat16* orow = obase + (size_t)(quad*4 + r) * (H_*VDIM_);
        #pragma unroll
        for (int nt = 0; nt < 8; ++nt)
            orow[nt*16 + ln] = __float2bfloat16(O[nt][r] * inv);
    }
}

// Diagnostic fallback
__global__ void fill_zero(float* p, int n) {
    int i = blockIdx.x * 256 + threadIdx.x;
    if (i < n) p[i] = 0.0f;
}

// ---------------------------------------------------------------------------
extern "C" void kernel_launch(void* const* d_in, const int* in_sizes, int n_in,
                              void* d_out, int out_size, void* d_ws, size_t ws_size,
                              hipStream_t stream)
{
    const float* x      = (const float*)d_in[0];
    const float* wq_w   = (const float*)d_in[1];
    const float* wq_b   = (const float*)d_in[2];
    const float* wkva_w = (const float*)d_in[3];
    const float* wkva_b = (const float*)d_in[4];
    const float* wkvb_w = (const float*)d_in[5];
    const float* wkvb_b = (const float*)d_in[6];
    const float* wo_w   = (const float*)d_in[7];
    const float* wo_b   = (const float*)d_in[8];
    const float* cs     = (const float*)d_in[9];
    const float* sn     = (const float*)d_in[10];

    // ---- workspace layout (bytes). att aliases xb+kvap+kvn; kr aliases wq_bf.
    const size_t q_b    = (size_t)NTOK * 3072 * 2;   // 50,331,648
    const size_t kn_b   = (size_t)NTOK * 2048 * 2;   // 33,554,432
    const size_t vt_b   = (size_t)H_ * 128 * NTOK * 2; // 33,554,432
    const size_t xb_b   = (size_t)NTOK * 1024 * 2;   // 16,777,216
    const size_t kvap_b = (size_t)NTOK * 640 * 2;    // 10,485,760
    const size_t kvn_b  = (size_t)NTOK * 512 * 2;    //  8,388,608
    const size_t wq_b_b = (size_t)3072 * 1024 * 2;   //  6,291,456 (also holds kr)
    const size_t wkva_b_b = (size_t)640 * 1024 * 2;  //  1,310,720
    const size_t wkvb_b_b = (size_t)4096 * 512 * 2;  //  4,194,304
    const size_t wo_b_b   = (size_t)1024 * 2048 * 2; //  4,194,304
    const size_t bias_b   = 4096;
    const size_t need = q_b + kn_b + vt_b + xb_b + kvap_b + kvn_b +
                        wq_b_b + wkva_b_b + wkvb_b_b + wo_b_b + bias_b; // 169,086,976

    if (ws_size < need) {
        fill_zero<<<(out_size + 255) / 256, 256, 0, stream>>>((float*)d_out, out_size);
        return;
    }

    char* p = (char*)d_ws;
    __hip_bfloat16* q    = (__hip_bfloat16*)p;             p += q_b;
    __hip_bfloat16* kn   = (__hip_bfloat16*)p;             p += kn_b;
    __hip_bfloat16* vt   = (__hip_bfloat16*)p;             p += vt_b;
    char*           dynr = p;                              // xb | kvap | kvn (att aliases)
    __hip_bfloat16* xb   = (__hip_bfloat16*)p;             p += xb_b;
    __hip_bfloat16* kvap = (__hip_bfloat16*)p;             p += kvap_b;
    __hip_bfloat16* kvn  = (__hip_bfloat16*)p;             p += kvn_b;
    __hip_bfloat16* wq_bf = (__hip_bfloat16*)p;            // kr aliases this later
    __hip_bfloat16* kr    = (__hip_bfloat16*)p;            p += wq_b_b;
    __hip_bfloat16* wkva_bf = (__hip_bfloat16*)p;          p += wkva_b_b;
    __hip_bfloat16* wkvb_bf = (__hip_bfloat16*)p;          p += wkvb_b_b;
    __hip_bfloat16* wo_bf   = (__hip_bfloat16*)p;          p += wo_b_b;
    float*          bias_pad = (float*)p;
    __hip_bfloat16* attb = (__hip_bfloat16*)dynr;          // (NTOK,2048) bf16
    float*          out  = (float*)d_out;

    // 1) conversions
    cvt_bf16<<<NTOK*1024/4/256, 256, 0, stream>>>(x, xb, NTOK*1024);
    cvt_bf16<<<3072*1024/4/256, 256, 0, stream>>>(wq_w, wq_bf, 3072*1024);
    cvt_bf16<<<4096*512/4/256, 256, 0, stream>>>(wkvb_w, wkvb_bf, 4096*512);
    cvt_bf16<<<1024*2048/4/256, 256, 0, stream>>>(wo_w, wo_bf, 1024*2048);
    cvt_pad_kva<<<640*1024/4/256, 256, 0, stream>>>(wkva_w, wkva_b, wkva_bf, bias_pad);

    // 2) q = x @ wq^T + b   (8192 x 3072, K=1024)
    gemm_mfma<__hip_bfloat16, 0><<<dim3(3072/128, NTOK/128), 256, 0, stream>>>(
        xb, 1024, wq_bf, 1024, wq_b, q, 3072, 1024, nullptr);
    // 3) kv_a = x @ wkva^T + b  (8192 x 640 padded, K=1024)
    gemm_mfma<__hip_bfloat16, 0><<<dim3(640/128, NTOK/128), 256, 0, stream>>>(
        xb, 1024, wkva_bf, 1024, bias_pad, kvap, 640, 1024, nullptr);
    // 4) RoPE on q
    rope_q<<<NTOK, 512, 0, stream>>>(q, cs, sn);
    // 5) rmsnorm + rope-k  (kvap -> kvn, kr; wq_bf dead -> kr reuses it)
    rmsnorm_ropek<<<NTOK, 256, 0, stream>>>(kvap, kvn, kr, cs, sn);
    // 6) kv_b: kvn @ wkvb^T + b -> kn (k_nope) + vt (V transposed)
    gemm_mfma<__hip_bfloat16, 1><<<dim3(4096/128, NTOK/128), 256, 0, stream>>>(
        kvn, 512, wkvb_bf, 512, wkvb_b, kn, 0, 512, vt);
    // 7) attention (writes att over xb/kvap/kvn region — all dead)
    attn_mfma<<<dim3(T_/64, H_, B_), 256, 0, stream>>>(q, kn, kr, vt, attb);
    // 8) out = att @ wo^T + b  (8192 x 1024, K=2048)
    gemm_mfma<float, 0><<<dim3(1024/128, NTOK/128), 256, 0, stream>>>(
        attb, 2048, wo_bf, 2048, wo_b, out, 1024, 2048, nullptr);
}